// Round 3
// baseline (85.025 us; speedup 1.0000x reference)
//
#include <hip/hip_runtime.h>

// out[b] = 0.75 * sum_i x[b,i] * s[i],  s[i] = sum_h W[h,i]
// x: [2048, 8192] f32 ; W: [8192, 8192] f32 ; out: [2048] f32

#define I_SIZE 8192
#define H_SIZE 8192
#define BATCH  2048

// ---- Kernel 1: flat streaming column-sum of W into s[8192] ----------------
// 1024 blocks x 256 threads = 262144 threads. Grid-stride in float4 units:
// stride = 262144 float4 = 1Mi floats == 0 (mod 8192), so thread gid always
// samples columns (gid*4) mod 8192 -> accumulate 64 samples in registers,
// then 4 atomicAdds. Whole grid reads one contiguous 4 MB slab per step.
#define CS_BLOCKS 1024
#define CS_THREADS ((size_t)CS_BLOCKS * 256)   // 262144
#define CS_ITERS  (( (size_t)H_SIZE * I_SIZE / 4) / CS_THREADS)  // 64

__global__ __launch_bounds__(256) void colsum_kernel(const float* __restrict__ W,
                                                     float* __restrict__ s) {
    const size_t gid = (size_t)blockIdx.x * 256 + threadIdx.x;
    const float4* Wf = reinterpret_cast<const float4*>(W);

    float4 acc = make_float4(0.f, 0.f, 0.f, 0.f);
#pragma unroll 16
    for (size_t k = 0; k < CS_ITERS; ++k) {
        float4 v = Wf[gid + k * CS_THREADS];
        acc.x += v.x; acc.y += v.y; acc.z += v.z; acc.w += v.w;
    }
    const int col = (int)((gid * 4) & (I_SIZE - 1));
    atomicAdd(&s[col + 0], acc.x);
    atomicAdd(&s[col + 1], acc.y);
    atomicAdd(&s[col + 2], acc.z);
    atomicAdd(&s[col + 3], acc.w);
}

// ---- Kernel 2: out[r] = 0.75 * dot(x[r], s), 4 rows per block -------------
// 512 blocks x 256 threads. Each s float4 load feeds 4 independent FMA
// chains; x rows are contiguous 32 KB sweeps.
__global__ __launch_bounds__(256) void rowdot_kernel(const float* __restrict__ x,
                                                     const float* __restrict__ s,
                                                     float* __restrict__ out) {
    const int t = threadIdx.x;
    const int r0 = blockIdx.x * 4;
    const float* x0 = x + (size_t)r0 * I_SIZE;
    const float* x1 = x0 + I_SIZE;
    const float* x2 = x1 + I_SIZE;
    const float* x3 = x2 + I_SIZE;

    float a0 = 0.f, a1 = 0.f, a2 = 0.f, a3 = 0.f;
#pragma unroll
    for (int j = 0; j < 8; ++j) {
        const int i = t * 4 + j * 1024;
        const float4 sv = *reinterpret_cast<const float4*>(s + i);
        const float4 v0 = *reinterpret_cast<const float4*>(x0 + i);
        const float4 v1 = *reinterpret_cast<const float4*>(x1 + i);
        const float4 v2 = *reinterpret_cast<const float4*>(x2 + i);
        const float4 v3 = *reinterpret_cast<const float4*>(x3 + i);
        a0 += v0.x * sv.x + v0.y * sv.y + v0.z * sv.z + v0.w * sv.w;
        a1 += v1.x * sv.x + v1.y * sv.y + v1.z * sv.z + v1.w * sv.w;
        a2 += v2.x * sv.x + v2.y * sv.y + v2.z * sv.z + v2.w * sv.w;
        a3 += v3.x * sv.x + v3.y * sv.y + v3.z * sv.z + v3.w * sv.w;
    }

    // wave-64 butterfly reduce on all four accumulators
#pragma unroll
    for (int off = 32; off; off >>= 1) {
        a0 += __shfl_down(a0, off, 64);
        a1 += __shfl_down(a1, off, 64);
        a2 += __shfl_down(a2, off, 64);
        a3 += __shfl_down(a3, off, 64);
    }

    __shared__ float p[4][4];   // [wave][row]
    const int lane = t & 63, wid = t >> 6;
    if (lane == 0) { p[wid][0] = a0; p[wid][1] = a1; p[wid][2] = a2; p[wid][3] = a3; }
    __syncthreads();
    if (t < 4)
        out[r0 + t] = 0.75f * (p[0][t] + p[1][t] + p[2][t] + p[3][t]);
}

extern "C" void kernel_launch(void* const* d_in, const int* in_sizes, int n_in,
                              void* d_out, int out_size, void* d_ws, size_t ws_size,
                              hipStream_t stream) {
    const float* x = (const float*)d_in[0];   // [BATCH, I_SIZE]
    const float* W = (const float*)d_in[1];   // [H_SIZE, I_SIZE]
    float* out = (float*)d_out;               // [BATCH]
    float* s   = (float*)d_ws;                // [I_SIZE] column sums

    hipMemsetAsync(s, 0, I_SIZE * sizeof(float), stream);
    colsum_kernel<<<CS_BLOCKS, 256, 0, stream>>>(W, s);
    rowdot_kernel<<<BATCH / 4, 256, 0, stream>>>(x, s, out);
}

// Round 4
// 83.751 us; speedup vs baseline: 1.0152x; 1.0152x over previous
//
#include <hip/hip_runtime.h>

// out[b] = 0.75 * sum_i x[b,i] * s[i],  s[i] = sum_h W[h,i]
// x: [2048, 8192] f32 ; W: [8192, 8192] f32 ; out: [2048] f32
//
// 3 dispatches, NO atomics, NO memset:
//   A: flat streaming colsum -> per-thread float4 partial (4 MB, contiguous)
//   B: reduce 128 partials/column -> s[8192]  (4 MB read, LLC-hot)
//   C: rowdot (R1-proven shape: 2048 blocks, 1 row/block)

#define I_SIZE 8192
#define H_SIZE 8192
#define BATCH  2048

#define CS_BLOCKS 1024
#define CS_THREADS ((size_t)CS_BLOCKS * 256)                     // 262144
#define CS_ITERS  (((size_t)H_SIZE * I_SIZE / 4) / CS_THREADS)   // 64

// ---- Stage A: W column partial-sums, non-atomic ---------------------------
// Thread gid sums 64 float4s at stride 1Mi floats (== 0 mod 8192, so all 64
// samples are the same 4 columns). Store the partial contiguously.
__global__ __launch_bounds__(256) void colsum_partial_kernel(
    const float* __restrict__ W, float4* __restrict__ partial) {
    const size_t gid = (size_t)blockIdx.x * 256 + threadIdx.x;
    const float4* Wf = reinterpret_cast<const float4*>(W);

    float4 acc = make_float4(0.f, 0.f, 0.f, 0.f);
#pragma unroll 16
    for (size_t k = 0; k < CS_ITERS; ++k) {
        float4 v = Wf[gid + k * CS_THREADS];
        acc.x += v.x; acc.y += v.y; acc.z += v.z; acc.w += v.w;
    }
    partial[gid] = acc;   // plain coalesced store, no atomic
}

// ---- Stage B: reduce partials -> s ----------------------------------------
// Flat float index into partial: f = gid*4 + comp; column(f) = f mod 8192,
// j-th partial of float-column c lives at f = c + j*8192, j in [0,128).
// 32 blocks x 256 threads = 8192 threads, one float-column each.
__global__ __launch_bounds__(256) void colsum_reduce_kernel(
    const float* __restrict__ partialF, float* __restrict__ s) {
    const int c = blockIdx.x * 256 + threadIdx.x;
    float acc = 0.f;
#pragma unroll 16
    for (int j = 0; j < 128; ++j)
        acc += partialF[(size_t)c + (size_t)j * I_SIZE];
    s[c] = acc;
}

// ---- Stage C: out[b] = 0.75 * dot(x[b], s) — R1-proven shape --------------
__global__ __launch_bounds__(256) void rowdot_kernel(const float* __restrict__ x,
                                                     const float* __restrict__ s,
                                                     float* __restrict__ out) {
    const int b = blockIdx.x;
    const float* xr = x + (size_t)b * I_SIZE;

    float acc = 0.f;
#pragma unroll
    for (int i = threadIdx.x * 4; i < I_SIZE; i += 256 * 4) {
        float4 xv = *reinterpret_cast<const float4*>(xr + i);
        float4 sv = *reinterpret_cast<const float4*>(s + i);
        acc += xv.x * sv.x + xv.y * sv.y + xv.z * sv.z + xv.w * sv.w;
    }

#pragma unroll
    for (int off = 32; off; off >>= 1)
        acc += __shfl_down(acc, off, 64);

    __shared__ float partial[4];
    const int lane = threadIdx.x & 63;
    const int wid  = threadIdx.x >> 6;
    if (lane == 0) partial[wid] = acc;
    __syncthreads();
    if (threadIdx.x == 0)
        out[b] = 0.75f * (partial[0] + partial[1] + partial[2] + partial[3]);
}

extern "C" void kernel_launch(void* const* d_in, const int* in_sizes, int n_in,
                              void* d_out, int out_size, void* d_ws, size_t ws_size,
                              hipStream_t stream) {
    const float* x = (const float*)d_in[0];   // [BATCH, I_SIZE]
    const float* W = (const float*)d_in[1];   // [H_SIZE, I_SIZE]
    float* out = (float*)d_out;               // [BATCH]

    float4* partial = (float4*)d_ws;                          // 4 MiB
    float*  s       = (float*)((char*)d_ws + (4u << 20));     // 32 KiB

    colsum_partial_kernel<<<CS_BLOCKS, 256, 0, stream>>>(W, partial);
    colsum_reduce_kernel<<<32, 256, 0, stream>>>((const float*)partial, s);
    rowdot_kernel<<<BATCH, 256, 0, stream>>>(x, s, out);
}